// Round 15
// baseline (210.307 us; speedup 1.0000x reference)
//
#include <hip/hip_runtime.h>

// Problem constants (fixed by setup_inputs)
#define BB 8
#define CIN 64
#define COUT 64
#define NN 2048
#define TT 13
#define KTT 3
#define LL 11
#define CL 704                         // COUT*LL
#define HP_SIZE 11534336LL             // B*COUT*N*L

// ws layout (bytes): fbuf 65536 | maxf 32 | tab4 262144 | w0pk 24576 | Apan | Bpan
#define WS_TAB_OFF 65568ULL
#define WS_W0PK_OFF 327712ULL
#define WS_APAN_OFF 352288ULL
#define WS_BPAN_OFF 23420960ULL        // APAN_OFF + 23068672
#define WS_NEED (23420960ULL + 67108864ULL)

typedef _Float16 f16;
typedef __attribute__((ext_vector_type(8))) _Float16 f16x8;
typedef __attribute__((ext_vector_type(2))) _Float16 f16x2;
typedef __attribute__((ext_vector_type(4))) float f32x4;

__device__ __forceinline__ unsigned int pk16(float a, float b) {
  f16 ha = (f16)a, hb = (f16)b;                    // RTN converts
  unsigned short ua = __builtin_bit_cast(unsigned short, ha);
  unsigned short ub = __builtin_bit_cast(unsigned short, hb);
  return (unsigned int)ua | ((unsigned int)ub << 16);
}
__device__ __forceinline__ f16x2 as_h2(unsigned int u) {
  return __builtin_bit_cast(f16x2, u);
}

// ---------------------------------------------------------------------------
// Kernel 0: pack w0 into ci-pair v2f16 form, once.
// ---------------------------------------------------------------------------
__global__ __launch_bounds__(256) void k_pack(const float* __restrict__ w0,
                                              unsigned int* __restrict__ w0pk_g) {
  int tid = blockIdx.x * 256 + threadIdx.x;        // 6144 total
  int c = tid & 63, r = tid >> 6;                  // r = cip*3+kt, 0..95
  int kt = r % 3, cip = r / 3;
  float ev = w0[c * 192 + cip * 6 + kt];
  float od = w0[c * 192 + cip * 6 + 3 + kt];
  w0pk_g[r * 64 + c] = pk16(ev, od);
}

// ---------------------------------------------------------------------------
// Kernel 1: conv0 via v_dot2_f32_f16 -> fp16 A panels (16-row-frag layout) + f.
// A panel: Apan[(b*11+mt)*64+ks] tile of 2048 f16 = [fr4][lane64][kk8];
// lane = kgrp*16 + row16; element = h[n = ks*32+kgrp*8+kk][m = mt*64+fr*16+row16]
// ---------------------------------------------------------------------------
__global__ __launch_bounds__(512, 4) void k_conv(
    const float* __restrict__ x, const unsigned int* __restrict__ w0pk_g,
    const float* __restrict__ b0, const float* __restrict__ w1,
    f16* __restrict__ Apan, float* __restrict__ f) {
  __shared__ unsigned int w0pk[96 * 64];       // 24 KB
  __shared__ unsigned int xspk[32 * 8 * 16];   // 16 KB
  __shared__ f16 As[704 * 10];                 // 14 KB
  const int tid = threadIdx.x;
  const int b = blockIdx.x >> 8;
  const int n0 = (blockIdx.x & 255) << 3;

#pragma unroll
  for (int i = 0; i < 12; ++i) w0pk[i * 512 + tid] = w0pk_g[i * 512 + tid];

#pragma unroll
  for (int i = 0; i < 7; ++i) {
    int task = i * 512 + tid;                  // 3328 total
    if (task < 3328) {
      int cip = task / 104, rem = task - cip * 104;
      long long base = (long long)(b * 64 + 2 * cip) * 26624 + n0 * 13 + rem;
      float ev = x[base];
      float od = x[base + 26624];
      int n = rem / 13, t = rem - n * 13;
      xspk[(cip * 8 + n) * 16 + t] = pk16(ev, od);
    }
  }
  __syncthreads();

  const int c = tid & 63, w = tid >> 6;
  float acc[11];
  const float bias = b0[c];
#pragma unroll
  for (int l = 0; l < 11; ++l) acc[l] = bias;

  for (int cip = 0; cip < 32; ++cip) {
    const unsigned int* xr = &xspk[(cip * 8 + w) * 16];
    uint4 xa = *(const uint4*)xr;
    uint4 xb = *(const uint4*)(xr + 4);
    uint4 xc = *(const uint4*)(xr + 8);
    unsigned int x13[13] = {xa.x, xa.y, xa.z, xa.w, xb.x, xb.y, xb.z, xb.w,
                            xc.x, xc.y, xc.z, xc.w, xr[12]};
    f16x2 wk0 = as_h2(w0pk[(cip * 3 + 0) * 64 + c]);
    f16x2 wk1 = as_h2(w0pk[(cip * 3 + 1) * 64 + c]);
    f16x2 wk2 = as_h2(w0pk[(cip * 3 + 2) * 64 + c]);
#pragma unroll
    for (int l = 0; l < 11; ++l) {
      acc[l] = __builtin_amdgcn_fdot2(as_h2(x13[l]), wk0, acc[l], false);
      acc[l] = __builtin_amdgcn_fdot2(as_h2(x13[l + 1]), wk1, acc[l], false);
      acc[l] = __builtin_amdgcn_fdot2(as_h2(x13[l + 2]), wk2, acc[l], false);
    }
  }

  float p = 0.f;
#pragma unroll
  for (int l = 0; l < 11; ++l) p = fmaf(acc[l], w1[c * 11 + l], p);
#pragma unroll
  for (int off = 32; off; off >>= 1) p += __shfl_xor(p, off, 64);
  if (c == 0) f[b * 2048 + n0 + w] = p;

#pragma unroll
  for (int l = 0; l < 11; ++l) As[(c * 11 + l) * 10 + w] = (f16)acc[l];
  __syncthreads();

  // panel write: this block covers ks, kgrp, kk = 0..7 (= w dim in As)
  const int ks = n0 >> 5, kgrp = (n0 >> 3) & 3;
  const unsigned int* As32 = (const unsigned int*)As;
#pragma unroll
  for (int i = 0; i < 2; ++i) {
    int m = i * 512 + tid;
    if (m < 704) {
      uint4 v;
      v.x = As32[m * 5 + 0];
      v.y = As32[m * 5 + 1];
      v.z = As32[m * 5 + 2];
      v.w = As32[m * 5 + 3];
      int mt = m >> 6, fr = (m >> 4) & 3, r16 = m & 15;
      long long base = ((long long)(b * 11 + mt) * 64 + ks) * 2048 +
                       fr * 512 + (kgrp * 16 + r16) * 8;
      *(uint4*)&Apan[base] = v;
    }
  }
}

// ---------------------------------------------------------------------------
// Kernel 2: per-batch max of f
// ---------------------------------------------------------------------------
__global__ __launch_bounds__(256) void k_maxf(const float* __restrict__ f,
                                              float* __restrict__ maxf) {
  const int b = blockIdx.x, tid = threadIdx.x;
  float m = -1e30f;
  for (int i = tid; i < 2048; i += 256) m = fmaxf(m, f[b * 2048 + i]);
#pragma unroll
  for (int off = 32; off; off >>= 1) m = fmaxf(m, __shfl_xor(m, off, 64));
  __shared__ float red[4];
  if ((tid & 63) == 0) red[tid >> 6] = m;
  __syncthreads();
  if (tid == 0) maxf[b] = fmaxf(fmaxf(red[0], red[1]), fmaxf(red[2], red[3]));
}

// ---------------------------------------------------------------------------
// Kernel 3: softmax row sums + exp-factor table tab4 = (En, E2n, Rq, Sq).
// att[n][q] = max(En_n*Rq_q, E2n_n*Sq_q)  (exact: pos-branch wins iff s>=0)
// ---------------------------------------------------------------------------
__global__ __launch_bounds__(256) void k_rowsum(const float* __restrict__ f,
                                                const float* __restrict__ maxf,
                                                float4* __restrict__ tab4) {
  __shared__ float fs[2048];
  const int b = blockIdx.x >> 9;
  const int q0 = (blockIdx.x & 511) << 2;
  const int tid = threadIdx.x;
#pragma unroll
  for (int i = 0; i < 8; ++i) fs[i * 256 + tid] = f[b * 2048 + i * 256 + tid];
  __syncthreads();
  const int lane = tid & 63, wid = tid >> 6;
  const int q = q0 + wid;
  const float fq = fs[q];
  const float mb = maxf[b];
  float t = fq + mb;
  const float m = t >= 0.f ? t : 0.2f * t;
  float sum = 0.f;
  for (int j = lane; j < 2048; j += 64) {
    float v = fq + fs[j];
    v = v >= 0.f ? v : 0.2f * v;
    sum += __expf(v - m);
  }
#pragma unroll
  for (int off = 32; off; off >>= 1) sum += __shfl_xor(sum, off, 64);
  if (lane == 0) {
    float rq = 1.0f / sum;
    float En = __expf(fq - mb);
    float E2 = __expf(0.2f * fq);
    float Rq = t >= 0.f ? rq : rq * __expf(0.8f * t);
    float Sq = rq * __expf(0.2f * fq - m);
    tab4[b * 2048 + q] = make_float4(En, E2, Rq, Sq);
  }
}

// ---------------------------------------------------------------------------
// Kernel 4: build att fp32 (+ optionally Bpan f16, GEMM-ready layout).
// Block = (b, ks): 32 n-rows x all 2048 q. Thread owns q = tid + 256j (8 q).
// Bpan[b][ks][kgrp4][q2048][kk8] f16: thread writes 4x16B per q (coalesced).
// att[n][q]: lanes = consecutive q (coalesced 1KB rows). Write-bound kernel.
// ---------------------------------------------------------------------------
template <int WITH_BPAN>
__global__ __launch_bounds__(256) void k_build(const float4* __restrict__ tab4,
                                               float* __restrict__ att,
                                               f16* __restrict__ Bpan) {
  const int b = blockIdx.x >> 6, ks = blockIdx.x & 63;
  const int tid = threadIdx.x;
  __shared__ float2 Etb[32];
  if (tid < 32) {
    float4 v = tab4[b * 2048 + ks * 32 + tid];
    Etb[tid] = make_float2(v.x, v.y);
  }
  __syncthreads();
  float En[32], E2[32];
#pragma unroll
  for (int i = 0; i < 32; ++i) { En[i] = Etb[i].x; E2[i] = Etb[i].y; }

  float* ab = att + ((long long)(b * 2048 + ks * 32)) * 2048;
  f16* bp = Bpan + (((long long)(b * 64 + ks)) * 4) * 2048 * 8;

#pragma unroll
  for (int j = 0; j < 8; ++j) {
    const int q = tid + j * 256;
    float4 t4 = tab4[b * 2048 + q];
    const float Rq = t4.z, Sq = t4.w;
#pragma unroll
    for (int kg = 0; kg < 4; ++kg) {
      float v[8];
#pragma unroll
      for (int kk = 0; kk < 8; ++kk) {
        int n = kg * 8 + kk;
        float val = fmaxf(En[n] * Rq, E2[n] * Sq);
        v[kk] = val;
        ab[(long long)n * 2048 + q] = val;
      }
      if (WITH_BPAN) {
        uint4 w;
        w.x = pk16(v[0], v[1]);
        w.y = pk16(v[2], v[3]);
        w.z = pk16(v[4], v[5]);
        w.w = pk16(v[6], v[7]);
        *(uint4*)&bp[((long long)kg * 2048 + q) * 8] = w;
      }
    }
  }
}

// ---------------------------------------------------------------------------
// Kernel 5 (fast path): pure-load 16x16x32 fp16 MFMA GEMM. No LDS, no
// barriers, no VALU B-build: A and B fragments loaded directly via dwordx4
// (panel layouts == fragment layouts). Block: 256 thr = 4 q-waves;
// wave = 4 mfrag x 2 nf; acc 32 VGPR; 4 blocks/CU (launch_bounds(256,4)).
// Grid p = (G%8) + 8*((G/8)*11 + mt), G = b*16+qt: the 11 mt-siblings of a
// (b,qt) share p%8 -> same XCD -> 512KB B-slice is L2-resident (11x reuse).
// ---------------------------------------------------------------------------
__global__ __launch_bounds__(256, 4) void k_gemm(const f16* __restrict__ Apan,
                                                 const f16* __restrict__ Bpan,
                                                 float* __restrict__ out) {
  const int p = blockIdx.x;
  const int x = p & 7, r = p >> 3;
  const int mt = r % 11, Gh = r / 11;
  const int G = Gh * 8 + x;
  const int b = G >> 4, qt = G & 15;

  const int tid = threadIdx.x;
  const int qw = tid >> 6, lane = tid & 63;
  const int l15 = lane & 15, l4 = lane >> 4;
  const int q0 = qt * 128 + qw * 32 + l15;

  const f16* Ab = Apan + ((long long)(b * 11 + mt) * 64) * 2048 + lane * 8;
  const f16* Bb = Bpan + (((long long)(b * 64) * 4 + l4) * 2048 + q0) * 8;

  f32x4 acc[4][2];
#pragma unroll
  for (int fr = 0; fr < 4; ++fr)
#pragma unroll
    for (int nf = 0; nf < 2; ++nf) acc[fr][nf] = (f32x4){0.f, 0.f, 0.f, 0.f};

  // prefetched pipeline: current (c*, d*), next (loaded mid-iteration)
  f16x8 ca0 = *(const f16x8*)(Ab);
  f16x8 ca1 = *(const f16x8*)(Ab + 512);
  f16x8 ca2 = *(const f16x8*)(Ab + 1024);
  f16x8 ca3 = *(const f16x8*)(Ab + 1536);
  f16x8 cb0 = *(const f16x8*)(Bb);
  f16x8 cb1 = *(const f16x8*)(Bb + 128);           // +16 q * 8

  for (int ks = 0; ks < 64; ++ks) {
    f16x8 na0 = ca0, na1 = ca1, na2 = ca2, na3 = ca3, nb0 = cb0, nb1 = cb1;
    if (ks < 63) {
      const f16* at = Ab + (ks + 1) * 2048;
      const f16* bt = Bb + (long long)(ks + 1) * 65536;   // 4*2048*8
      na0 = *(const f16x8*)(at);
      na1 = *(const f16x8*)(at + 512);
      na2 = *(const f16x8*)(at + 1024);
      na3 = *(const f16x8*)(at + 1536);
      nb0 = *(const f16x8*)(bt);
      nb1 = *(const f16x8*)(bt + 128);
    }
#pragma unroll
    for (int nf = 0; nf < 2; ++nf) {
      f16x8 bv = nf == 0 ? cb0 : cb1;
      acc[0][nf] = __builtin_amdgcn_mfma_f32_16x16x32_f16(ca0, bv, acc[0][nf], 0, 0, 0);
      acc[1][nf] = __builtin_amdgcn_mfma_f32_16x16x32_f16(ca1, bv, acc[1][nf], 0, 0, 0);
      acc[2][nf] = __builtin_amdgcn_mfma_f32_16x16x32_f16(ca2, bv, acc[2][nf], 0, 0, 0);
      acc[3][nf] = __builtin_amdgcn_mfma_f32_16x16x32_f16(ca3, bv, acc[3][nf], 0, 0, 0);
    }
    ca0 = na0; ca1 = na1; ca2 = na2; ca3 = na3; cb0 = nb0; cb1 = nb1;
  }

  // epilogue: C/D layout col(q)=lane&15, row(m)=(lane>>4)*4+r
  float* ob = out + (long long)b * COUT * NN * LL;
#pragma unroll
  for (int fr = 0; fr < 4; ++fr) {
#pragma unroll
    for (int rr = 0; rr < 4; ++rr) {
      int m = mt * 64 + fr * 16 + l4 * 4 + rr;
      int c = m / 11, l2 = m - c * 11;
      float* orow = ob + (long long)c * NN * LL + l2;
#pragma unroll
      for (int nf = 0; nf < 2; ++nf) {
        int q = q0 + nf * 16;
        orow[(long long)q * LL] = acc[fr][nf][rr];
      }
    }
  }
}

// ---------------------------------------------------------------------------
// Kernel 5b (fallback, ws too small): R14's in-kernel-B GEMM (known good).
// ---------------------------------------------------------------------------
__global__ __launch_bounds__(256, 4) void k_gemm_fb(const f16* __restrict__ Apan,
                                                    const float4* __restrict__ tab4,
                                                    float* __restrict__ out) {
  __shared__ __align__(16) float2 Etab[2048];
  const int p = blockIdx.x;
  const int g = p % 88, qt = p / 88;
  const int b = g / 11, mt = g % 11;
  const int tid = threadIdx.x;
  const int qw = tid >> 6, lane = tid & 63;
  const int l15 = lane & 15, l4 = lane >> 4;
  const f16* Ab = Apan + ((long long)(b * 11 + mt) * 64) * 2048 + lane * 8;
  const float4* tb = tab4 + (long long)b * NN;
#pragma unroll
  for (int i = 0; i < 8; ++i) {
    int idx = i * 256 + tid;
    float4 v = tb[idx];
    Etab[idx] = make_float2(v.x, v.y);
  }
  const int q0 = qt * 128 + qw * 32 + l15;
  float Rq0, Sq0, Rq1, Sq1;
  { float4 t4 = tb[q0];      Rq0 = t4.z; Sq0 = t4.w; }
  { float4 t4 = tb[q0 + 16]; Rq1 = t4.z; Sq1 = t4.w; }
  __syncthreads();
  f32x4 acc[4][2];
#pragma unroll
  for (int fr = 0; fr < 4; ++fr)
#pragma unroll
    for (int nf = 0; nf < 2; ++nf) acc[fr][nf] = (f32x4){0.f, 0.f, 0.f, 0.f};
  f16x8 c0 = *(const f16x8*)(Ab);
  f16x8 c1 = *(const f16x8*)(Ab + 512);
  f16x8 c2 = *(const f16x8*)(Ab + 1024);
  f16x8 c3 = *(const f16x8*)(Ab + 1536);
  for (int ks = 0; ks < 64; ++ks) {
    f16x8 n0 = c0, n1 = c1, n2 = c2, n3 = c3;
    if (ks < 63) {
      const f16* at = Ab + (ks + 1) * 2048;
      n0 = *(const f16x8*)(at);
      n1 = *(const f16x8*)(at + 512);
      n2 = *(const f16x8*)(at + 1024);
      n3 = *(const f16x8*)(at + 1536);
    }
    const int nb = ks * 32 + l4 * 8;
    const float4* ep = (const float4*)&Etab[nb];
    float4 e0 = ep[0], e1 = ep[1], e2 = ep[2], e3 = ep[3];
    float En[8] = {e0.x, e0.z, e1.x, e1.z, e2.x, e2.z, e3.x, e3.z};
    float E2[8] = {e0.y, e0.w, e1.y, e1.w, e2.y, e2.w, e3.y, e3.w};
#pragma unroll
    for (int nf = 0; nf < 2; ++nf) {
      const float Rq = nf == 0 ? Rq0 : Rq1;
      const float Sq = nf == 0 ? Sq0 : Sq1;
      f16x8 bv;
#pragma unroll
      for (int u = 0; u < 8; ++u) bv[u] = (f16)fmaxf(En[u] * Rq, E2[u] * Sq);
      acc[0][nf] = __builtin_amdgcn_mfma_f32_16x16x32_f16(c0, bv, acc[0][nf], 0, 0, 0);
      acc[1][nf] = __builtin_amdgcn_mfma_f32_16x16x32_f16(c1, bv, acc[1][nf], 0, 0, 0);
      acc[2][nf] = __builtin_amdgcn_mfma_f32_16x16x32_f16(c2, bv, acc[2][nf], 0, 0, 0);
      acc[3][nf] = __builtin_amdgcn_mfma_f32_16x16x32_f16(c3, bv, acc[3][nf], 0, 0, 0);
    }
    c0 = n0; c1 = n1; c2 = n2; c3 = n3;
  }
  float* ob = out + (long long)b * COUT * NN * LL;
#pragma unroll
  for (int fr = 0; fr < 4; ++fr) {
#pragma unroll
    for (int rr = 0; rr < 4; ++rr) {
      int m = mt * 64 + fr * 16 + l4 * 4 + rr;
      int c = m / 11, l2 = m - c * 11;
      float* orow = ob + (long long)c * NN * LL + l2;
#pragma unroll
      for (int nf = 0; nf < 2; ++nf)
        orow[(long long)(q0 + nf * 16) * LL] = acc[fr][nf][rr];
    }
  }
}

// ---------------------------------------------------------------------------
extern "C" void kernel_launch(void* const* d_in, const int* in_sizes, int n_in,
                              void* d_out, int out_size, void* d_ws, size_t ws_size,
                              hipStream_t stream) {
  const float* x  = (const float*)d_in[0];
  const float* w0 = (const float*)d_in[1];
  const float* b0 = (const float*)d_in[2];
  const float* w1 = (const float*)d_in[3];

  float* fbuf = (float*)d_ws;                                   // 16384 f
  float* maxf = fbuf + BB * NN;                                 // 8 f
  float4* tab4 = (float4*)((char*)d_ws + WS_TAB_OFF);           // 16384 float4
  unsigned int* w0pk_g = (unsigned int*)((char*)d_ws + WS_W0PK_OFF);  // 24 KB
  f16* Apan = (f16*)((char*)d_ws + WS_APAN_OFF);                // 23.07 MB
  f16* Bpan = (f16*)((char*)d_ws + WS_BPAN_OFF);                // 67.1 MB

  float* hp  = (float*)d_out;
  float* att = hp + HP_SIZE;

  k_pack<<<dim3(24), dim3(256), 0, stream>>>(w0, w0pk_g);
  k_conv<<<dim3(BB * 256), dim3(512), 0, stream>>>(x, w0pk_g, b0, w1, Apan, fbuf);
  k_maxf<<<dim3(BB), dim3(256), 0, stream>>>(fbuf, maxf);
  k_rowsum<<<dim3(BB * 512), dim3(256), 0, stream>>>(fbuf, maxf, tab4);
  if (ws_size >= WS_NEED) {
    k_build<1><<<dim3(BB * 64), dim3(256), 0, stream>>>(tab4, att, Bpan);
    k_gemm<<<dim3(1408), dim3(256), 0, stream>>>(Apan, Bpan, hp);
  } else {
    k_build<0><<<dim3(BB * 64), dim3(256), 0, stream>>>(tab4, att, Bpan);
    k_gemm_fb<<<dim3(88 * 16), dim3(256), 0, stream>>>(Apan, tab4, hp);
  }
}

// Round 16
// 169.602 us; speedup vs baseline: 1.2400x; 1.2400x over previous
//
#include <hip/hip_runtime.h>

// Problem constants (fixed by setup_inputs)
#define BB 8
#define CIN 64
#define COUT 64
#define NN 2048
#define TT 13
#define KTT 3
#define LL 11
#define CL 704                         // COUT*LL
#define HP_SIZE 11534336LL             // B*COUT*N*L

// ws layout (bytes): fbuf 65536 | maxf 32 | tab4 262144 | tabp 65536 | w0pk 24576 | Apan
#define WS_TAB_OFF 65568ULL
#define WS_TABP_OFF 327712ULL
#define WS_W0PK_OFF 393248ULL
#define WS_APAN_OFF 417824ULL

typedef _Float16 f16;
typedef __attribute__((ext_vector_type(8))) _Float16 f16x8;
typedef __attribute__((ext_vector_type(2))) _Float16 f16x2;
typedef __attribute__((ext_vector_type(4))) float f32x4;

__device__ __forceinline__ unsigned int pk16(float a, float b) {
  f16 ha = (f16)a, hb = (f16)b;                    // RTN converts
  unsigned short ua = __builtin_bit_cast(unsigned short, ha);
  unsigned short ub = __builtin_bit_cast(unsigned short, hb);
  return (unsigned int)ua | ((unsigned int)ub << 16);
}
__device__ __forceinline__ f16x2 as_h2(unsigned int u) {
  return __builtin_bit_cast(f16x2, u);
}

// ---------------------------------------------------------------------------
// Kernel 0: pack w0 into ci-pair v2f16 form, once.
// ---------------------------------------------------------------------------
__global__ __launch_bounds__(256) void k_pack(const float* __restrict__ w0,
                                              unsigned int* __restrict__ w0pk_g) {
  int tid = blockIdx.x * 256 + threadIdx.x;        // 6144 total
  int c = tid & 63, r = tid >> 6;                  // r = cip*3+kt, 0..95
  int kt = r % 3, cip = r / 3;
  float ev = w0[c * 192 + cip * 6 + kt];
  float od = w0[c * 192 + cip * 6 + 3 + kt];
  w0pk_g[r * 64 + c] = pk16(ev, od);
}

// ---------------------------------------------------------------------------
// Kernel 1: conv0 via v_dot2_f32_f16 -> fp16 A panels (16-row-frag layout) + f.
// A panel: Apan[(b*11+mt)*64+ks] tile of 2048 f16 = [fr4][lane64][kk8];
// lane = kgrp*16 + row16; element = h[n = ks*32+kgrp*8+kk][m = mt*64+fr*16+row16]
// ---------------------------------------------------------------------------
__global__ __launch_bounds__(512, 4) void k_conv(
    const float* __restrict__ x, const unsigned int* __restrict__ w0pk_g,
    const float* __restrict__ b0, const float* __restrict__ w1,
    f16* __restrict__ Apan, float* __restrict__ f) {
  __shared__ unsigned int w0pk[96 * 64];       // 24 KB
  __shared__ unsigned int xspk[32 * 8 * 16];   // 16 KB
  __shared__ f16 As[704 * 10];                 // 14 KB
  const int tid = threadIdx.x;
  const int b = blockIdx.x >> 8;
  const int n0 = (blockIdx.x & 255) << 3;

#pragma unroll
  for (int i = 0; i < 12; ++i) w0pk[i * 512 + tid] = w0pk_g[i * 512 + tid];

#pragma unroll
  for (int i = 0; i < 7; ++i) {
    int task = i * 512 + tid;                  // 3328 total
    if (task < 3328) {
      int cip = task / 104, rem = task - cip * 104;
      long long base = (long long)(b * 64 + 2 * cip) * 26624 + n0 * 13 + rem;
      float ev = x[base];
      float od = x[base + 26624];
      int n = rem / 13, t = rem - n * 13;
      xspk[(cip * 8 + n) * 16 + t] = pk16(ev, od);
    }
  }
  __syncthreads();

  const int c = tid & 63, w = tid >> 6;
  float acc[11];
  const float bias = b0[c];
#pragma unroll
  for (int l = 0; l < 11; ++l) acc[l] = bias;

  for (int cip = 0; cip < 32; ++cip) {
    const unsigned int* xr = &xspk[(cip * 8 + w) * 16];
    uint4 xa = *(const uint4*)xr;
    uint4 xb = *(const uint4*)(xr + 4);
    uint4 xc = *(const uint4*)(xr + 8);
    unsigned int x13[13] = {xa.x, xa.y, xa.z, xa.w, xb.x, xb.y, xb.z, xb.w,
                            xc.x, xc.y, xc.z, xc.w, xr[12]};
    f16x2 wk0 = as_h2(w0pk[(cip * 3 + 0) * 64 + c]);
    f16x2 wk1 = as_h2(w0pk[(cip * 3 + 1) * 64 + c]);
    f16x2 wk2 = as_h2(w0pk[(cip * 3 + 2) * 64 + c]);
#pragma unroll
    for (int l = 0; l < 11; ++l) {
      acc[l] = __builtin_amdgcn_fdot2(as_h2(x13[l]), wk0, acc[l], false);
      acc[l] = __builtin_amdgcn_fdot2(as_h2(x13[l + 1]), wk1, acc[l], false);
      acc[l] = __builtin_amdgcn_fdot2(as_h2(x13[l + 2]), wk2, acc[l], false);
    }
  }

  float p = 0.f;
#pragma unroll
  for (int l = 0; l < 11; ++l) p = fmaf(acc[l], w1[c * 11 + l], p);
#pragma unroll
  for (int off = 32; off; off >>= 1) p += __shfl_xor(p, off, 64);
  if (c == 0) f[b * 2048 + n0 + w] = p;

#pragma unroll
  for (int l = 0; l < 11; ++l) As[(c * 11 + l) * 10 + w] = (f16)acc[l];
  __syncthreads();

  // panel write: this block covers ks, kgrp, kk = 0..7 (= w dim in As)
  const int ks = n0 >> 5, kgrp = (n0 >> 3) & 3;
  const unsigned int* As32 = (const unsigned int*)As;
#pragma unroll
  for (int i = 0; i < 2; ++i) {
    int m = i * 512 + tid;
    if (m < 704) {
      uint4 v;
      v.x = As32[m * 5 + 0];
      v.y = As32[m * 5 + 1];
      v.z = As32[m * 5 + 2];
      v.w = As32[m * 5 + 3];
      int mt = m >> 6, fr = (m >> 4) & 3, r16 = m & 15;
      long long base = ((long long)(b * 11 + mt) * 64 + ks) * 2048 +
                       fr * 512 + (kgrp * 16 + r16) * 8;
      *(uint4*)&Apan[base] = v;
    }
  }
}

// ---------------------------------------------------------------------------
// Kernel 2: per-batch max of f
// ---------------------------------------------------------------------------
__global__ __launch_bounds__(256) void k_maxf(const float* __restrict__ f,
                                              float* __restrict__ maxf) {
  const int b = blockIdx.x, tid = threadIdx.x;
  float m = -1e30f;
  for (int i = tid; i < 2048; i += 256) m = fmaxf(m, f[b * 2048 + i]);
#pragma unroll
  for (int off = 32; off; off >>= 1) m = fmaxf(m, __shfl_xor(m, off, 64));
  __shared__ float red[4];
  if ((tid & 63) == 0) red[tid >> 6] = m;
  __syncthreads();
  if (tid == 0) maxf[b] = fmaxf(fmaxf(red[0], red[1]), fmaxf(red[2], red[3]));
}

// ---------------------------------------------------------------------------
// Kernel 3: softmax row sums + exp-factor tables.
// tab4 = (En, E2n, Rq, Sq) f32; tabp = packed f16x2 (En, E2n).
// att[n][q] = max(En_n*Rq_q, E2n_n*Sq_q)  (exact: pos-branch wins iff s>=0)
// ---------------------------------------------------------------------------
__global__ __launch_bounds__(256) void k_rowsum(const float* __restrict__ f,
                                                const float* __restrict__ maxf,
                                                float4* __restrict__ tab4,
                                                unsigned int* __restrict__ tabp) {
  __shared__ float fs[2048];
  const int b = blockIdx.x >> 9;
  const int q0 = (blockIdx.x & 511) << 2;
  const int tid = threadIdx.x;
#pragma unroll
  for (int i = 0; i < 8; ++i) fs[i * 256 + tid] = f[b * 2048 + i * 256 + tid];
  __syncthreads();
  const int lane = tid & 63, wid = tid >> 6;
  const int q = q0 + wid;
  const float fq = fs[q];
  const float mb = maxf[b];
  float t = fq + mb;
  const float m = t >= 0.f ? t : 0.2f * t;
  float sum = 0.f;
  for (int j = lane; j < 2048; j += 64) {
    float v = fq + fs[j];
    v = v >= 0.f ? v : 0.2f * v;
    sum += __expf(v - m);
  }
#pragma unroll
  for (int off = 32; off; off >>= 1) sum += __shfl_xor(sum, off, 64);
  if (lane == 0) {
    float rq = 1.0f / sum;
    float En = __expf(fq - mb);
    float E2 = __expf(0.2f * fq);
    float Rq = t >= 0.f ? rq : rq * __expf(0.8f * t);
    float Sq = rq * __expf(0.2f * fq - m);
    tab4[b * 2048 + q] = make_float4(En, E2, Rq, Sq);
    tabp[b * 2048 + q] = pk16(En, E2);
  }
}

// ---------------------------------------------------------------------------
// Kernel 4: barrier-free 16x16x32 fp16 MFMA GEMM (R13 structure) with
// f16-packed B-build (v_pk_mul + v_max, ~2x less VALU) and depth-2 A
// prefetch (two named register sets, unroll-2 main loop).
// Block: 256 thr = 4 q-waves; wave = 4 mfrag (64 rows) x 4 nf (64 q).
// Grid p: g = p%88 (b,mt), qt = p/88 -> 8 qt-siblings share XCD p%8.
// Fused balanced att stores: block owns ks where (ks*11)>>6 == mt.
// ---------------------------------------------------------------------------
__global__ __launch_bounds__(256, 3) void k_gemm(const f16* __restrict__ Apan,
                                                 const float4* __restrict__ tab4,
                                                 const unsigned int* __restrict__ tabp,
                                                 float* __restrict__ att,
                                                 float* __restrict__ out) {
  __shared__ __align__(16) unsigned int EtabP[2048];   // 8 KB packed (En,E2)

  const int p = blockIdx.x;
  const int g = p % 88, qt = p / 88;
  const int b = g / 11, mt = g % 11;

  const int tid = threadIdx.x;
  const int qw = tid >> 6, lane = tid & 63;
  const int l15 = lane & 15, l4 = lane >> 4;

  const f16* Ab = Apan + ((long long)(b * 11 + mt) * 64) * 2048 + lane * 8;
  const float4* tb = tab4 + (long long)b * NN;
  const unsigned int* tp = tabp + (long long)b * NN;

  // stage packed Etab (8 KB)
#pragma unroll
  for (int i = 0; i < 8; ++i) {
    int idx = i * 256 + tid;
    EtabP[idx] = tp[idx];
  }
  // per-nf q-side factors packed (Rq,Sq) f16x2
  const int q0 = qt * 256 + qw * 64 + l15;
  f16x2 rs0, rs1, rs2, rs3;
  { float4 t4 = tb[q0];      rs0 = as_h2(pk16(t4.z, t4.w)); }
  { float4 t4 = tb[q0 + 16]; rs1 = as_h2(pk16(t4.z, t4.w)); }
  { float4 t4 = tb[q0 + 32]; rs2 = as_h2(pk16(t4.z, t4.w)); }
  { float4 t4 = tb[q0 + 48]; rs3 = as_h2(pk16(t4.z, t4.w)); }
  __syncthreads();   // Etab ready; ONLY barrier in the kernel

  f32x4 acc[4][4];
#pragma unroll
  for (int fr = 0; fr < 4; ++fr)
#pragma unroll
    for (int nf = 0; nf < 4; ++nf) acc[fr][nf] = (f32x4){0.f, 0.f, 0.f, 0.f};

  // depth-2 A pipeline: set0 = even tiles, set1 = odd tiles
  f16x8 a0_0 = *(const f16x8*)(Ab);
  f16x8 a0_1 = *(const f16x8*)(Ab + 512);
  f16x8 a0_2 = *(const f16x8*)(Ab + 1024);
  f16x8 a0_3 = *(const f16x8*)(Ab + 1536);
  f16x8 a1_0 = *(const f16x8*)(Ab + 2048);
  f16x8 a1_1 = *(const f16x8*)(Ab + 2048 + 512);
  f16x8 a1_2 = *(const f16x8*)(Ab + 2048 + 1024);
  f16x8 a1_3 = *(const f16x8*)(Ab + 2048 + 1536);

  for (int ks = 0; ks < 64; ks += 2) {
    // ---------- tile ks (set 0) ----------
    {
      const int nb = ks * 32 + l4 * 8;
      uint4 e0 = *(const uint4*)&EtabP[nb];
      uint4 e1 = *(const uint4*)&EtabP[nb + 4];
      unsigned int ev[8] = {e0.x, e0.y, e0.z, e0.w, e1.x, e1.y, e1.z, e1.w};
      const bool owned = ((ks * 11) >> 6) == mt;
      const long long abase = ((long long)(b * 2048 + nb)) * 2048 + q0;
#pragma unroll
      for (int nf = 0; nf < 4; ++nf) {
        const f16x2 rs = nf == 0 ? rs0 : nf == 1 ? rs1 : nf == 2 ? rs2 : rs3;
        f16x8 bv;
#pragma unroll
        for (int u = 0; u < 8; ++u) {
          f16x2 pm = as_h2(ev[u]) * rs;            // v_pk_mul_f16
          bv[u] = pm[0] > pm[1] ? pm[0] : pm[1];   // v_max_f16
        }
        if (owned) {
          float* ap = att + abase + nf * 16;
#pragma unroll
          for (int u = 0; u < 8; ++u) ap[(long long)u * 2048] = (float)bv[u];
        }
        acc[0][nf] = __builtin_amdgcn_mfma_f32_16x16x32_f16(a0_0, bv, acc[0][nf], 0, 0, 0);
        acc[1][nf] = __builtin_amdgcn_mfma_f32_16x16x32_f16(a0_1, bv, acc[1][nf], 0, 0, 0);
        acc[2][nf] = __builtin_amdgcn_mfma_f32_16x16x32_f16(a0_2, bv, acc[2][nf], 0, 0, 0);
        acc[3][nf] = __builtin_amdgcn_mfma_f32_16x16x32_f16(a0_3, bv, acc[3][nf], 0, 0, 0);
      }
      // refill set 0 with tile ks+2 (clamped; redundant tail load harmless)
      const int kn = ks + 2 < 64 ? ks + 2 : 63;
      const f16* at = Ab + kn * 2048;
      a0_0 = *(const f16x8*)(at);
      a0_1 = *(const f16x8*)(at + 512);
      a0_2 = *(const f16x8*)(at + 1024);
      a0_3 = *(const f16x8*)(at + 1536);
    }
    // ---------- tile ks+1 (set 1) ----------
    {
      const int ks1 = ks + 1;
      const int nb = ks1 * 32 + l4 * 8;
      uint4 e0 = *(const uint4*)&EtabP[nb];
      uint4 e1 = *(const uint4*)&EtabP[nb + 4];
      unsigned int ev[8] = {e0.x, e0.y, e0.z, e0.w, e1.x, e1.y, e1.z, e1.w};
      const bool owned = ((ks1 * 11) >> 6) == mt;
      const long long abase = ((long long)(b * 2048 + nb)) * 2048 + q0;
#pragma unroll
      for (int nf = 0; nf < 4; ++nf) {
        const f16x2 rs = nf == 0 ? rs0 : nf == 1 ? rs1 : nf == 2 ? rs2 : rs3;
        f16x8 bv;
#pragma unroll
        for (int u = 0; u < 8; ++u) {
          f16x2 pm = as_h2(ev[u]) * rs;
          bv[u] = pm[0] > pm[1] ? pm[0] : pm[1];
        }
        if (owned) {
          float* ap = att + abase + nf * 16;
#pragma unroll
          for (int u = 0; u < 8; ++u) ap[(long long)u * 2048] = (float)bv[u];
        }
        acc[0][nf] = __builtin_amdgcn_mfma_f32_16x16x32_f16(a1_0, bv, acc[0][nf], 0, 0, 0);
        acc[1][nf] = __builtin_amdgcn_mfma_f32_16x16x32_f16(a1_1, bv, acc[1][nf], 0, 0, 0);
        acc[2][nf] = __builtin_amdgcn_mfma_f32_16x16x32_f16(a1_2, bv, acc[2][nf], 0, 0, 0);
        acc[3][nf] = __builtin_amdgcn_mfma_f32_16x16x32_f16(a1_3, bv, acc[3][nf], 0, 0, 0);
      }
      // refill set 1 with tile ks+3 (clamped)
      const int kn = ks + 3 < 64 ? ks + 3 : 63;
      const f16* at = Ab + kn * 2048;
      a1_0 = *(const f16x8*)(at);
      a1_1 = *(const f16x8*)(at + 512);
      a1_2 = *(const f16x8*)(at + 1024);
      a1_3 = *(const f16x8*)(at + 1536);
    }
  }

  // epilogue: C/D layout col(q)=lane&15, row(m)=(lane>>4)*4+r
  float* ob = out + (long long)b * COUT * NN * LL;
#pragma unroll
  for (int fr = 0; fr < 4; ++fr) {
#pragma unroll
    for (int r = 0; r < 4; ++r) {
      int m = mt * 64 + fr * 16 + l4 * 4 + r;
      int c = m / 11, l2 = m - c * 11;
      float* orow = ob + (long long)c * NN * LL + l2;
#pragma unroll
      for (int nf = 0; nf < 4; ++nf) {
        int q = q0 + nf * 16;
        orow[(long long)q * LL] = acc[fr][nf][r];
      }
    }
  }
}

// ---------------------------------------------------------------------------
extern "C" void kernel_launch(void* const* d_in, const int* in_sizes, int n_in,
                              void* d_out, int out_size, void* d_ws, size_t ws_size,
                              hipStream_t stream) {
  const float* x  = (const float*)d_in[0];
  const float* w0 = (const float*)d_in[1];
  const float* b0 = (const float*)d_in[2];
  const float* w1 = (const float*)d_in[3];

  float* fbuf = (float*)d_ws;                                   // 16384 f
  float* maxf = fbuf + BB * NN;                                 // 8 f
  float4* tab4 = (float4*)((char*)d_ws + WS_TAB_OFF);           // 16384 float4
  unsigned int* tabp = (unsigned int*)((char*)d_ws + WS_TABP_OFF);    // 64 KB
  unsigned int* w0pk_g = (unsigned int*)((char*)d_ws + WS_W0PK_OFF);  // 24 KB
  f16* Apan = (f16*)((char*)d_ws + WS_APAN_OFF);                // 23.07 MB

  float* hp  = (float*)d_out;
  float* att = hp + HP_SIZE;

  k_pack<<<dim3(24), dim3(256), 0, stream>>>(w0, w0pk_g);
  k_conv<<<dim3(BB * 256), dim3(512), 0, stream>>>(x, w0pk_g, b0, w1, Apan, fbuf);
  k_maxf<<<dim3(BB), dim3(256), 0, stream>>>(fbuf, maxf);
  k_rowsum<<<dim3(BB * 512), dim3(256), 0, stream>>>(fbuf, maxf, tab4, tabp);
  k_gemm<<<dim3(704), dim3(256), 0, stream>>>(Apan, tab4, tabp, att, hp);
}